// Round 1
// baseline (751.157 us; speedup 1.0000x reference)
//
#include <hip/hip_runtime.h>
#include <hip/hip_bf16.h>

#define NN 100000
#define NE 3200000
#define NF 512
#define NH 16
#define NC 16
#define EPSF 1e-12f

typedef unsigned short u16;

__device__ __forceinline__ float bf2f(u16 v) {
  return __uint_as_float(((unsigned int)v) << 16);
}
__device__ __forceinline__ u16 f2bf(float f) {
  unsigned int u = __float_as_uint(f);
  u += 0x7fffu + ((u >> 16) & 1u);   // round-to-nearest-even
  return (u16)(u >> 16);
}

// ---------------- Kernel A: h1 = relu(x@W1 + b1), rnorm1; also zero counts ----
// lane = (j, c2): j = output col (0..15), c2 = K-chunk (0..3, 128 elems each).
// W1 column slice lives in 128 VGPRs per lane; x row read via broadcast float4.
__global__ __launch_bounds__(256) void k_feat(const float* __restrict__ x,
    const float* __restrict__ W1, const float* __restrict__ b1,
    u16* __restrict__ h, float* __restrict__ rn, int* __restrict__ counts) {
  const int tid  = threadIdx.x;
  // fold: zero the CSR count array (stream-ordered before k_count)
  for (int g = blockIdx.x * blockDim.x + tid; g < NN; g += gridDim.x * blockDim.x)
    counts[g] = 0;

  const int lane = tid & 63;
  const int j    = lane & 15;
  const int c2   = lane >> 4;
  const int wid  = blockIdx.x * (blockDim.x >> 6) + (tid >> 6);
  const int nw   = gridDim.x * (blockDim.x >> 6);

  float w1r[128];
  #pragma unroll
  for (int t = 0; t < 128; ++t) w1r[t] = W1[(c2 * 128 + t) * NH + j];
  const float bias = b1[j];

  for (int row = wid; row < NN; row += nw) {
    const float4* xp = (const float4*)(x + (size_t)row * NF + c2 * 128);
    float a0 = 0.f, a1 = 0.f, a2 = 0.f, a3 = 0.f;
    #pragma unroll
    for (int t = 0; t < 32; ++t) {
      float4 v = xp[t];
      a0 = fmaf(v.x, w1r[4 * t + 0], a0);
      a1 = fmaf(v.y, w1r[4 * t + 1], a1);
      a2 = fmaf(v.z, w1r[4 * t + 2], a2);
      a3 = fmaf(v.w, w1r[4 * t + 3], a3);
    }
    float acc = (a0 + a1) + (a2 + a3);
    acc += __shfl_xor(acc, 16, 64);   // combine K-chunks
    acc += __shfl_xor(acc, 32, 64);
    float o = fmaxf(acc + bias, 0.0f);
    float ss = o * o;                 // row norm over 16 lanes
    ss += __shfl_xor(ss, 1, 64);
    ss += __shfl_xor(ss, 2, 64);
    ss += __shfl_xor(ss, 4, 64);
    ss += __shfl_xor(ss, 8, 64);
    float rv = 1.0f / fmaxf(sqrtf(ss), EPSF);
    if (lane < 16) h[(size_t)row * NH + j] = f2bf(o);
    if (lane == 0) rn[row] = rv;
  }
}

// ---------------- CSR build ----------------
__global__ void k_count(const int* __restrict__ dst, int* __restrict__ counts) {
  const int stride = gridDim.x * blockDim.x;
  for (int e = blockIdx.x * blockDim.x + threadIdx.x; e < NE; e += stride)
    atomicAdd(&counts[dst[e]], 1);
}

__global__ void k_scan1(const int* __restrict__ counts, int* __restrict__ bsum) {
  __shared__ int sm[256];
  const int tid = threadIdx.x;
  const int i = blockIdx.x * 256 + tid;
  sm[tid] = (i < NN) ? counts[i] : 0;
  __syncthreads();
  for (int s = 128; s > 0; s >>= 1) {
    if (tid < s) sm[tid] += sm[tid + s];
    __syncthreads();
  }
  if (tid == 0) bsum[blockIdx.x] = sm[0];
}

__global__ void k_scan2(int* __restrict__ bsum, int nb) {
  __shared__ int sm[512];
  const int tid = threadIdx.x;
  const int v = (tid < nb) ? bsum[tid] : 0;
  sm[tid] = v;
  __syncthreads();
  for (int s = 1; s < 512; s <<= 1) {
    int t = (tid >= s) ? sm[tid - s] : 0;
    __syncthreads();
    sm[tid] += t;
    __syncthreads();
  }
  if (tid < nb) bsum[tid] = sm[tid] - v;   // exclusive
}

__global__ void k_scan3(const int* __restrict__ counts, const int* __restrict__ bsum,
                        int* __restrict__ offs, int* __restrict__ cursor) {
  __shared__ int sm[256];
  const int tid = threadIdx.x;
  const int i = blockIdx.x * 256 + tid;
  const int v = (i < NN) ? counts[i] : 0;
  sm[tid] = v;
  __syncthreads();
  for (int s = 1; s < 256; s <<= 1) {
    int t = (tid >= s) ? sm[tid - s] : 0;
    __syncthreads();
    sm[tid] += t;
    __syncthreads();
  }
  const int excl = sm[tid] - v + bsum[blockIdx.x];
  if (i < NN) { offs[i] = excl; cursor[i] = excl; }
}

__global__ void k_fill(const int* __restrict__ srcs, const int* __restrict__ dsts,
                       int* __restrict__ cursor, int* __restrict__ csr) {
  const int stride = gridDim.x * blockDim.x;
  for (int e = blockIdx.x * blockDim.x + threadIdx.x; e < NE; e += stride) {
    const int d = dsts[e];
    const int slot = atomicAdd(&cursor[d], 1);
    csr[slot] = srcs[e];
  }
}

// ---------------- Prop: wave per node, 16 lanes per edge, 4 edges in flight ---
// Softmax shift skipped: logits in [-|beta|, |beta|]; out = (sum w*h_src)/(sum w).
// Self-loop = virtual edge i == deg with src = n.
template <bool FINAL>
__global__ __launch_bounds__(256) void k_prop(const u16* __restrict__ hp,
    const float* __restrict__ rnp, const int* __restrict__ csr,
    const int* __restrict__ offs, const int* __restrict__ cnts,
    const float* __restrict__ betap,
    u16* __restrict__ ho, float* __restrict__ rno,
    const float* __restrict__ W2, const float* __restrict__ b2,
    float* __restrict__ out) {
  const int tid  = threadIdx.x;
  const int lane = tid & 63;
  const int j    = lane & 15;
  const int es   = lane >> 4;
  const int wid  = blockIdx.x * (blockDim.x >> 6) + (tid >> 6);
  const int nw   = gridDim.x * (blockDim.x >> 6);
  const float beta = betap ? betap[0] : 1.0f;

  float w2r[16];
  float b2j = 0.f;
  if (FINAL) {
    #pragma unroll
    for (int k = 0; k < 16; ++k) w2r[k] = W2[k * NC + j];
    b2j = b2[j];
  }

  for (int n = wid; n < NN; n += nw) {
    const int off = offs[n];
    const int deg = cnts[n];
    const float hd  = bf2f(hp[(size_t)n * NH + j]);
    const float rnd = rnp[n];
    const float brd = beta * rnd;
    float acc = 0.f, ssum = 0.f;
    const int total = deg + 1;            // + self loop
    for (int i = es; i < total; i += 4) {
      const int src = (i < deg) ? csr[off + i] : n;
      const float hs  = bf2f(hp[(size_t)src * NH + j]);
      const float rns = rnp[src];
      float p = hs * hd;                  // 16-dim dot via 16-lane reduce
      p += __shfl_xor(p, 1, 64);
      p += __shfl_xor(p, 2, 64);
      p += __shfl_xor(p, 4, 64);
      p += __shfl_xor(p, 8, 64);
      const float w = __expf(brd * rns * p);
      acc = fmaf(w, hs, acc);
      ssum += w;
    }
    acc  += __shfl_xor(acc, 16, 64);      // combine the 4 edge slots
    acc  += __shfl_xor(acc, 32, 64);
    ssum += __shfl_xor(ssum, 16, 64);
    ssum += __shfl_xor(ssum, 32, 64);
    const float o = acc / ssum;

    if (!FINAL) {
      float ss = o * o;
      ss += __shfl_xor(ss, 1, 64);
      ss += __shfl_xor(ss, 2, 64);
      ss += __shfl_xor(ss, 4, 64);
      ss += __shfl_xor(ss, 8, 64);
      float rv = 1.0f / fmaxf(sqrtf(ss), EPSF);
      if (lane < 16) ho[(size_t)n * NH + j] = f2bf(o);
      if (lane == 0) rno[n] = rv;
    } else {
      // logits = o(row) @ W2 + b2, then log_softmax across 16 lanes
      float lg = b2j;
      #pragma unroll
      for (int k = 0; k < 16; ++k) {
        const float hk = __shfl(o, k, 64);
        lg = fmaf(hk, w2r[k], lg);
      }
      float m = lg;
      m = fmaxf(m, __shfl_xor(m, 1, 64));
      m = fmaxf(m, __shfl_xor(m, 2, 64));
      m = fmaxf(m, __shfl_xor(m, 4, 64));
      m = fmaxf(m, __shfl_xor(m, 8, 64));
      float e = __expf(lg - m);
      float se = e;
      se += __shfl_xor(se, 1, 64);
      se += __shfl_xor(se, 2, 64);
      se += __shfl_xor(se, 4, 64);
      se += __shfl_xor(se, 8, 64);
      const float res = lg - m - __logf(se);
      if (lane < 16) out[(size_t)n * NC + j] = res;
    }
  }
}

extern "C" void kernel_launch(void* const* d_in, const int* in_sizes, int n_in,
                              void* d_out, int out_size, void* d_ws, size_t ws_size,
                              hipStream_t stream) {
  const float* x     = (const float*)d_in[0];
  const int*   ei    = (const int*)d_in[1];
  const float* W1    = (const float*)d_in[2];
  const float* b1    = (const float*)d_in[3];
  const float* W2    = (const float*)d_in[4];
  const float* b2    = (const float*)d_in[5];
  const float* beta2 = (const float*)d_in[6];
  float* out = (float*)d_out;

  char* ws = (char*)d_ws;
  size_t o = 0;
  auto alloc = [&](size_t bytes) -> void* {
    o = (o + 255) & ~(size_t)255;
    void* p = ws + o;
    o += bytes;
    return p;
  };
  u16*   h1     = (u16*)alloc((size_t)NN * NH * 2);
  u16*   h2     = (u16*)alloc((size_t)NN * NH * 2);
  float* rn1    = (float*)alloc((size_t)NN * 4);
  float* rn2    = (float*)alloc((size_t)NN * 4);
  int*   counts = (int*)alloc((size_t)NN * 4);
  int*   offs   = (int*)alloc((size_t)NN * 4);
  int*   cursor = (int*)alloc((size_t)NN * 4);
  int*   bsum   = (int*)alloc(1024 * 4);
  int*   csr    = (int*)alloc((size_t)NE * 4);

  const int* esrc = ei;
  const int* edst = ei + NE;

  const int nb = (NN + 255) / 256;  // 391

  k_feat<<<2048, 256, 0, stream>>>(x, W1, b1, h1, rn1, counts);
  k_count<<<4096, 256, 0, stream>>>(edst, counts);
  k_scan1<<<nb, 256, 0, stream>>>(counts, bsum);
  k_scan2<<<1, 512, 0, stream>>>(bsum, nb);
  k_scan3<<<nb, 256, 0, stream>>>(counts, bsum, offs, cursor);
  k_fill<<<4096, 256, 0, stream>>>(esrc, edst, cursor, csr);
  k_prop<false><<<25000, 256, 0, stream>>>(h1, rn1, csr, offs, counts, nullptr,
                                           h2, rn2, nullptr, nullptr, nullptr);
  k_prop<true><<<25000, 256, 0, stream>>>(h2, rn2, csr, offs, counts, beta2,
                                          nullptr, nullptr, W2, b2, out);
}

// Round 2
// 641.996 us; speedup vs baseline: 1.1700x; 1.1700x over previous
//
#include <hip/hip_runtime.h>
#include <hip/hip_bf16.h>

#define NN 100000
#define NE 3200000
#define NF 512
#define NH 16
#define NC 16
#define EPSF 1e-12f

// k_fill temporal blocking: 8 dst-range passes, live CSR window 1.6 MB (L2-resident)
#define NPASS 8
#define RANGE ((NN + NPASS - 1) / NPASS)   // 12500
#define FILL_BLOCKS 2048                   // 8 blocks/CU * 256 CU -> all co-resident

typedef unsigned short u16;

__device__ __forceinline__ float bf2f(u16 v) {
  return __uint_as_float(((unsigned int)v) << 16);
}
__device__ __forceinline__ u16 f2bf(float f) {
  unsigned int u = __float_as_uint(f);
  u += 0x7fffu + ((u >> 16) & 1u);   // round-to-nearest-even
  return (u16)(u >> 16);
}

// ---------------- Kernel A: h1 = relu(x@W1 + b1), rnorm1; also zero counts ----
// lane = (j, c2): j = output col (0..15), c2 = K-chunk (0..3, 128 elems each).
// W1 column slice lives in 128 VGPRs per lane; x row read via broadcast float4.
__global__ __launch_bounds__(256) void k_feat(const float* __restrict__ x,
    const float* __restrict__ W1, const float* __restrict__ b1,
    u16* __restrict__ h, float* __restrict__ rn, int* __restrict__ counts) {
  const int tid  = threadIdx.x;
  // fold: zero the CSR count array (stream-ordered before k_count)
  for (int g = blockIdx.x * blockDim.x + tid; g < NN; g += gridDim.x * blockDim.x)
    counts[g] = 0;

  const int lane = tid & 63;
  const int j    = lane & 15;
  const int c2   = lane >> 4;
  const int wid  = blockIdx.x * (blockDim.x >> 6) + (tid >> 6);
  const int nw   = gridDim.x * (blockDim.x >> 6);

  float w1r[128];
  #pragma unroll
  for (int t = 0; t < 128; ++t) w1r[t] = W1[(c2 * 128 + t) * NH + j];
  const float bias = b1[j];

  for (int row = wid; row < NN; row += nw) {
    const float4* xp = (const float4*)(x + (size_t)row * NF + c2 * 128);
    float a0 = 0.f, a1 = 0.f, a2 = 0.f, a3 = 0.f;
    #pragma unroll
    for (int t = 0; t < 32; ++t) {
      float4 v = xp[t];
      a0 = fmaf(v.x, w1r[4 * t + 0], a0);
      a1 = fmaf(v.y, w1r[4 * t + 1], a1);
      a2 = fmaf(v.z, w1r[4 * t + 2], a2);
      a3 = fmaf(v.w, w1r[4 * t + 3], a3);
    }
    float acc = (a0 + a1) + (a2 + a3);
    acc += __shfl_xor(acc, 16, 64);   // combine K-chunks
    acc += __shfl_xor(acc, 32, 64);
    float o = fmaxf(acc + bias, 0.0f);
    float ss = o * o;                 // row norm over 16 lanes
    ss += __shfl_xor(ss, 1, 64);
    ss += __shfl_xor(ss, 2, 64);
    ss += __shfl_xor(ss, 4, 64);
    ss += __shfl_xor(ss, 8, 64);
    float rv = 1.0f / fmaxf(sqrtf(ss), EPSF);
    if (lane < 16) h[(size_t)row * NH + j] = f2bf(o);
    if (lane == 0) rn[row] = rv;
  }
}

// ---------------- CSR build ----------------
__global__ void k_count(const int* __restrict__ dst, int* __restrict__ counts) {
  const int stride = gridDim.x * blockDim.x;
  for (int e = blockIdx.x * blockDim.x + threadIdx.x; e < NE; e += stride)
    atomicAdd(&counts[dst[e]], 1);
}

__global__ void k_scan1(const int* __restrict__ counts, int* __restrict__ bsum) {
  __shared__ int sm[256];
  const int tid = threadIdx.x;
  const int i = blockIdx.x * 256 + tid;
  sm[tid] = (i < NN) ? counts[i] : 0;
  __syncthreads();
  for (int s = 128; s > 0; s >>= 1) {
    if (tid < s) sm[tid] += sm[tid + s];
    __syncthreads();
  }
  if (tid == 0) bsum[blockIdx.x] = sm[0];
}

__global__ void k_scan2(int* __restrict__ bsum, int nb) {
  __shared__ int sm[512];
  const int tid = threadIdx.x;
  const int v = (tid < nb) ? bsum[tid] : 0;
  sm[tid] = v;
  __syncthreads();
  for (int s = 1; s < 512; s <<= 1) {
    int t = (tid >= s) ? sm[tid - s] : 0;
    __syncthreads();
    sm[tid] += t;
    __syncthreads();
  }
  if (tid < nb) bsum[tid] = sm[tid] - v;   // exclusive
}

__global__ void k_scan3(const int* __restrict__ counts, const int* __restrict__ bsum,
                        int* __restrict__ offs, int* __restrict__ cursor) {
  __shared__ int sm[256];
  const int tid = threadIdx.x;
  const int i = blockIdx.x * 256 + tid;
  const int v = (i < NN) ? counts[i] : 0;
  sm[tid] = v;
  __syncthreads();
  for (int s = 1; s < 256; s <<= 1) {
    int t = (tid >= s) ? sm[tid - s] : 0;
    __syncthreads();
    sm[tid] += t;
    __syncthreads();
  }
  const int excl = sm[tid] - v + bsum[blockIdx.x];
  if (i < NN) { offs[i] = excl; cursor[i] = excl; }
}

// Temporally-blocked CSR fill: pass p handles dst in [p*RANGE, (p+1)*RANGE).
// Live scatter window = RANGE*avg_deg*4B = 1.6 MB -> stays in per-XCD L2, so
// each 64B csr line absorbs all ~16 slot-writes before writeback (write amp 16x -> 1x).
// Grid sized to full co-residency so blocks sweep passes in soft lockstep.
__global__ __launch_bounds__(256) void k_fill(const int* __restrict__ srcs,
                                              const int* __restrict__ dsts,
                                              int* __restrict__ cursor,
                                              int* __restrict__ csr) {
  const int stride = gridDim.x * blockDim.x;
  const int t0 = blockIdx.x * blockDim.x + threadIdx.x;
  for (int p = 0; p < NPASS; ++p) {
    const int lo = p * RANGE;
    const int hi = lo + RANGE;
    for (int e = t0; e < NE; e += stride) {
      const int d = dsts[e];
      if (d >= lo && d < hi) {
        const int slot = atomicAdd(&cursor[d], 1);
        csr[slot] = srcs[e];
      }
    }
  }
}

// ---------------- Prop: wave per node, 16 lanes per edge, 4 edges in flight ---
// Softmax shift skipped: logits in [-|beta|, |beta|]; out = (sum w*h_src)/(sum w).
// Self-loop = virtual edge i == deg with src = n.
template <bool FINAL>
__global__ __launch_bounds__(256) void k_prop(const u16* __restrict__ hp,
    const float* __restrict__ rnp, const int* __restrict__ csr,
    const int* __restrict__ offs, const int* __restrict__ cnts,
    const float* __restrict__ betap,
    u16* __restrict__ ho, float* __restrict__ rno,
    const float* __restrict__ W2, const float* __restrict__ b2,
    float* __restrict__ out) {
  const int tid  = threadIdx.x;
  const int lane = tid & 63;
  const int j    = lane & 15;
  const int es   = lane >> 4;
  const int wid  = blockIdx.x * (blockDim.x >> 6) + (tid >> 6);
  const int nw   = gridDim.x * (blockDim.x >> 6);
  const float beta = betap ? betap[0] : 1.0f;

  float w2r[16];
  float b2j = 0.f;
  if (FINAL) {
    #pragma unroll
    for (int k = 0; k < 16; ++k) w2r[k] = W2[k * NC + j];
    b2j = b2[j];
  }

  for (int n = wid; n < NN; n += nw) {
    const int off = offs[n];
    const int deg = cnts[n];
    const float hd  = bf2f(hp[(size_t)n * NH + j]);
    const float rnd = rnp[n];
    const float brd = beta * rnd;
    float acc = 0.f, ssum = 0.f;
    const int total = deg + 1;            // + self loop
    for (int i = es; i < total; i += 4) {
      const int src = (i < deg) ? csr[off + i] : n;
      const float hs  = bf2f(hp[(size_t)src * NH + j]);
      const float rns = rnp[src];
      float p = hs * hd;                  // 16-dim dot via 16-lane reduce
      p += __shfl_xor(p, 1, 64);
      p += __shfl_xor(p, 2, 64);
      p += __shfl_xor(p, 4, 64);
      p += __shfl_xor(p, 8, 64);
      const float w = __expf(brd * rns * p);
      acc = fmaf(w, hs, acc);
      ssum += w;
    }
    acc  += __shfl_xor(acc, 16, 64);      // combine the 4 edge slots
    acc  += __shfl_xor(acc, 32, 64);
    ssum += __shfl_xor(ssum, 16, 64);
    ssum += __shfl_xor(ssum, 32, 64);
    const float o = acc / ssum;

    if (!FINAL) {
      float ss = o * o;
      ss += __shfl_xor(ss, 1, 64);
      ss += __shfl_xor(ss, 2, 64);
      ss += __shfl_xor(ss, 4, 64);
      ss += __shfl_xor(ss, 8, 64);
      float rv = 1.0f / fmaxf(sqrtf(ss), EPSF);
      if (lane < 16) ho[(size_t)n * NH + j] = f2bf(o);
      if (lane == 0) rno[n] = rv;
    } else {
      // logits = o(row) @ W2 + b2, then log_softmax across 16 lanes
      float lg = b2j;
      #pragma unroll
      for (int k = 0; k < 16; ++k) {
        const float hk = __shfl(o, k, 64);
        lg = fmaf(hk, w2r[k], lg);
      }
      float m = lg;
      m = fmaxf(m, __shfl_xor(m, 1, 64));
      m = fmaxf(m, __shfl_xor(m, 2, 64));
      m = fmaxf(m, __shfl_xor(m, 4, 64));
      m = fmaxf(m, __shfl_xor(m, 8, 64));
      float e = __expf(lg - m);
      float se = e;
      se += __shfl_xor(se, 1, 64);
      se += __shfl_xor(se, 2, 64);
      se += __shfl_xor(se, 4, 64);
      se += __shfl_xor(se, 8, 64);
      const float res = lg - m - __logf(se);
      if (lane < 16) out[(size_t)n * NC + j] = res;
    }
  }
}

extern "C" void kernel_launch(void* const* d_in, const int* in_sizes, int n_in,
                              void* d_out, int out_size, void* d_ws, size_t ws_size,
                              hipStream_t stream) {
  const float* x     = (const float*)d_in[0];
  const int*   ei    = (const int*)d_in[1];
  const float* W1    = (const float*)d_in[2];
  const float* b1    = (const float*)d_in[3];
  const float* W2    = (const float*)d_in[4];
  const float* b2    = (const float*)d_in[5];
  const float* beta2 = (const float*)d_in[6];
  float* out = (float*)d_out;

  char* ws = (char*)d_ws;
  size_t o = 0;
  auto alloc = [&](size_t bytes) -> void* {
    o = (o + 255) & ~(size_t)255;
    void* p = ws + o;
    o += bytes;
    return p;
  };
  u16*   h1     = (u16*)alloc((size_t)NN * NH * 2);
  u16*   h2     = (u16*)alloc((size_t)NN * NH * 2);
  float* rn1    = (float*)alloc((size_t)NN * 4);
  float* rn2    = (float*)alloc((size_t)NN * 4);
  int*   counts = (int*)alloc((size_t)NN * 4);
  int*   offs   = (int*)alloc((size_t)NN * 4);
  int*   cursor = (int*)alloc((size_t)NN * 4);
  int*   bsum   = (int*)alloc(1024 * 4);
  int*   csr    = (int*)alloc((size_t)NE * 4);

  const int* esrc = ei;
  const int* edst = ei + NE;

  const int nb = (NN + 255) / 256;  // 391

  k_feat<<<2048, 256, 0, stream>>>(x, W1, b1, h1, rn1, counts);
  k_count<<<4096, 256, 0, stream>>>(edst, counts);
  k_scan1<<<nb, 256, 0, stream>>>(counts, bsum);
  k_scan2<<<1, 512, 0, stream>>>(bsum, nb);
  k_scan3<<<nb, 256, 0, stream>>>(counts, bsum, offs, cursor);
  k_fill<<<FILL_BLOCKS, 256, 0, stream>>>(esrc, edst, cursor, csr);
  k_prop<false><<<25000, 256, 0, stream>>>(h1, rn1, csr, offs, counts, nullptr,
                                           h2, rn2, nullptr, nullptr, nullptr);
  k_prop<true><<<25000, 256, 0, stream>>>(h2, rn2, csr, offs, counts, beta2,
                                          nullptr, nullptr, W2, b2, out);
}

// Round 3
// 570.053 us; speedup vs baseline: 1.3177x; 1.1262x over previous
//
#include <hip/hip_runtime.h>
#include <hip/hip_bf16.h>

#define NN 100000
#define NE 3200000
#define NF 512
#define NH 16
#define NC 16
#define EPSF 1e-12f

// k_fill temporal blocking: 8 dst-range passes, live CSR window 1.6 MB (L2-resident)
#define NPASS 8
#define RANGE ((NN + NPASS - 1) / NPASS)   // 12500
#define FILL_BLOCKS 2048                   // 8 blocks/CU * 256 CU -> all co-resident

typedef unsigned short u16;

__device__ __forceinline__ float bf2f(u16 v) {
  return __uint_as_float(((unsigned int)v) << 16);
}
__device__ __forceinline__ u16 f2bf(float f) {
  unsigned int u = __float_as_uint(f);
  u += 0x7fffu + ((u >> 16) & 1u);   // round-to-nearest-even
  return (u16)(u >> 16);
}

// ---------------- Kernel A: h1 = relu(x@W1 + b1), rnorm1; also zero counts ----
// Block = 4 waves = 64 rows. Wave q owns K-quarter [q*128,(q+1)*128) for all 64
// rows (lane = row). W1 address is wave-uniform -> s_load through K$ (SGPRs,
// zero VGPR cost); FMA = v_fmac(vgpr_x, sgpr_w). Cross-wave K-combine via LDS.
__global__ __launch_bounds__(256) void k_feat(const float* __restrict__ x,
    const float* __restrict__ W1, const float* __restrict__ b1,
    u16* __restrict__ h, float* __restrict__ rn, int* __restrict__ counts) {
  const int tid = threadIdx.x;
  // fold: zero the CSR count array (stream-ordered before k_count)
  for (int g = blockIdx.x * 256 + tid; g < NN; g += gridDim.x * 256)
    counts[g] = 0;

  __shared__ float part[4][64][20];   // [quarter][row][j], stride 20 (float4-aligned pad)

  const int lane = tid & 63;
  const int q = __builtin_amdgcn_readfirstlane(tid >> 6);  // wave-uniform K-quarter
  const int base = blockIdx.x * 64;
  int row = base + lane;
  if (row >= NN) row = NN - 1;        // clamp: dead rows compute garbage, writes guarded

  const float* wq = W1 + q * 128 * NH;                     // uniform
  const float4* xp = (const float4*)(x + (size_t)row * NF + q * 128);

  float acc[16];
  #pragma unroll
  for (int j = 0; j < 16; ++j) acc[j] = 0.f;

  #pragma unroll 2
  for (int kk = 0; kk < 32; ++kk) {   // 32 float4 steps of 4 k each
    const float4 xv = xp[kk];
    #pragma unroll
    for (int dk = 0; dk < 4; ++dk) {
      const float* wrow = wq + (kk * 4 + dk) * NH;         // uniform -> s_load
      const float xs = (dk == 0) ? xv.x : (dk == 1) ? xv.y : (dk == 2) ? xv.z : xv.w;
      #pragma unroll
      for (int j = 0; j < 16; ++j)
        acc[j] = fmaf(xs, wrow[j], acc[j]);
    }
  }

  #pragma unroll
  for (int j4 = 0; j4 < 4; ++j4)
    *(float4*)&part[q][lane][j4 * 4] =
        make_float4(acc[j4 * 4], acc[j4 * 4 + 1], acc[j4 * 4 + 2], acc[j4 * 4 + 3]);
  __syncthreads();

  // epilogue: thread (r2, jg) sums 4 quarters for 4 j's, relu, norm, store
  const int r2 = tid >> 2;            // 0..63
  const int jg = (tid & 3) * 4;       // j-group base
  const int orow = base + r2;
  float o[4];
  #pragma unroll
  for (int jj = 0; jj < 4; ++jj) {
    const int j = jg + jj;
    float s = part[0][r2][j] + part[1][r2][j] + part[2][r2][j] + part[3][r2][j];
    o[jj] = fmaxf(s + b1[j], 0.f);
  }
  float ss = o[0] * o[0] + o[1] * o[1] + o[2] * o[2] + o[3] * o[3];
  ss += __shfl_xor(ss, 1, 64);
  ss += __shfl_xor(ss, 2, 64);
  const float rv = 1.0f / fmaxf(sqrtf(ss), EPSF);
  if (orow < NN) {
    ushort4 hv;
    hv.x = f2bf(o[0]); hv.y = f2bf(o[1]); hv.z = f2bf(o[2]); hv.w = f2bf(o[3]);
    *(ushort4*)(h + (size_t)orow * NH + jg) = hv;
    if ((tid & 3) == 0) rn[orow] = rv;
  }
}

// ---------------- CSR build ----------------
__global__ void k_count(const int* __restrict__ dst, int* __restrict__ counts) {
  const int stride = gridDim.x * blockDim.x;
  for (int e = blockIdx.x * blockDim.x + threadIdx.x; e < NE; e += stride)
    atomicAdd(&counts[dst[e]], 1);
}

__global__ void k_scan1(const int* __restrict__ counts, int* __restrict__ bsum) {
  __shared__ int sm[256];
  const int tid = threadIdx.x;
  const int i = blockIdx.x * 256 + tid;
  sm[tid] = (i < NN) ? counts[i] : 0;
  __syncthreads();
  for (int s = 128; s > 0; s >>= 1) {
    if (tid < s) sm[tid] += sm[tid + s];
    __syncthreads();
  }
  if (tid == 0) bsum[blockIdx.x] = sm[0];
}

__global__ void k_scan2(int* __restrict__ bsum, int nb) {
  __shared__ int sm[512];
  const int tid = threadIdx.x;
  const int v = (tid < nb) ? bsum[tid] : 0;
  sm[tid] = v;
  __syncthreads();
  for (int s = 1; s < 512; s <<= 1) {
    int t = (tid >= s) ? sm[tid - s] : 0;
    __syncthreads();
    sm[tid] += t;
    __syncthreads();
  }
  if (tid < nb) bsum[tid] = sm[tid] - v;   // exclusive
}

__global__ void k_scan3(const int* __restrict__ counts, const int* __restrict__ bsum,
                        int* __restrict__ offs, int* __restrict__ cursor) {
  __shared__ int sm[256];
  const int tid = threadIdx.x;
  const int i = blockIdx.x * 256 + tid;
  const int v = (i < NN) ? counts[i] : 0;
  sm[tid] = v;
  __syncthreads();
  for (int s = 1; s < 256; s <<= 1) {
    int t = (tid >= s) ? sm[tid - s] : 0;
    __syncthreads();
    sm[tid] += t;
    __syncthreads();
  }
  const int excl = sm[tid] - v + bsum[blockIdx.x];
  if (i < NN) { offs[i] = excl; cursor[i] = excl; }
}

// Temporally-blocked CSR fill: pass p handles dst in [p*RANGE, (p+1)*RANGE).
// Live scatter window ~1.6 MB -> L2-resident; write amp 16x -> 1x.
__global__ __launch_bounds__(256) void k_fill(const int* __restrict__ srcs,
                                              const int* __restrict__ dsts,
                                              int* __restrict__ cursor,
                                              int* __restrict__ csr) {
  const int stride = gridDim.x * blockDim.x;
  const int t0 = blockIdx.x * blockDim.x + threadIdx.x;
  for (int p = 0; p < NPASS; ++p) {
    const int lo = p * RANGE;
    const int hi = lo + RANGE;
    for (int e = t0; e < NE; e += stride) {
      const int d = dsts[e];
      if (d >= lo && d < hi) {
        const int slot = atomicAdd(&cursor[d], 1);
        csr[slot] = srcs[e];
      }
    }
  }
}

// ---------------- Prop: wave per node, 16 lanes per edge, 4 edges in flight ---
// Softmax shift skipped: logits in [-|beta|, |beta|]; out = (sum w*h_src)/(sum w).
// Self-loop = virtual edge i == deg with src = n.
template <bool FINAL>
__global__ __launch_bounds__(256) void k_prop(const u16* __restrict__ hp,
    const float* __restrict__ rnp, const int* __restrict__ csr,
    const int* __restrict__ offs, const int* __restrict__ cnts,
    const float* __restrict__ betap,
    u16* __restrict__ ho, float* __restrict__ rno,
    const float* __restrict__ W2, const float* __restrict__ b2,
    float* __restrict__ out) {
  const int tid  = threadIdx.x;
  const int lane = tid & 63;
  const int j    = lane & 15;
  const int es   = lane >> 4;
  const int wid  = blockIdx.x * (blockDim.x >> 6) + (tid >> 6);
  const int nw   = gridDim.x * (blockDim.x >> 6);
  const float beta = betap ? betap[0] : 1.0f;

  float w2r[16];
  float b2j = 0.f;
  if (FINAL) {
    #pragma unroll
    for (int k = 0; k < 16; ++k) w2r[k] = W2[k * NC + j];
    b2j = b2[j];
  }

  for (int n = wid; n < NN; n += nw) {
    const int off = offs[n];
    const int deg = cnts[n];
    const float hd  = bf2f(hp[(size_t)n * NH + j]);
    const float rnd = rnp[n];
    const float brd = beta * rnd;
    float acc = 0.f, ssum = 0.f;
    const int total = deg + 1;            // + self loop
    for (int i = es; i < total; i += 4) {
      const int src = (i < deg) ? csr[off + i] : n;
      const float hs  = bf2f(hp[(size_t)src * NH + j]);
      const float rns = rnp[src];
      float p = hs * hd;                  // 16-dim dot via 16-lane reduce
      p += __shfl_xor(p, 1, 64);
      p += __shfl_xor(p, 2, 64);
      p += __shfl_xor(p, 4, 64);
      p += __shfl_xor(p, 8, 64);
      const float w = __expf(brd * rns * p);
      acc = fmaf(w, hs, acc);
      ssum += w;
    }
    acc  += __shfl_xor(acc, 16, 64);      // combine the 4 edge slots
    acc  += __shfl_xor(acc, 32, 64);
    ssum += __shfl_xor(ssum, 16, 64);
    ssum += __shfl_xor(ssum, 32, 64);
    const float o = acc / ssum;

    if (!FINAL) {
      float ss = o * o;
      ss += __shfl_xor(ss, 1, 64);
      ss += __shfl_xor(ss, 2, 64);
      ss += __shfl_xor(ss, 4, 64);
      ss += __shfl_xor(ss, 8, 64);
      float rv = 1.0f / fmaxf(sqrtf(ss), EPSF);
      if (lane < 16) ho[(size_t)n * NH + j] = f2bf(o);
      if (lane == 0) rno[n] = rv;
    } else {
      // logits = o(row) @ W2 + b2, then log_softmax across 16 lanes
      float lg = b2j;
      #pragma unroll
      for (int k = 0; k < 16; ++k) {
        const float hk = __shfl(o, k, 64);
        lg = fmaf(hk, w2r[k], lg);
      }
      float m = lg;
      m = fmaxf(m, __shfl_xor(m, 1, 64));
      m = fmaxf(m, __shfl_xor(m, 2, 64));
      m = fmaxf(m, __shfl_xor(m, 4, 64));
      m = fmaxf(m, __shfl_xor(m, 8, 64));
      float e = __expf(lg - m);
      float se = e;
      se += __shfl_xor(se, 1, 64);
      se += __shfl_xor(se, 2, 64);
      se += __shfl_xor(se, 4, 64);
      se += __shfl_xor(se, 8, 64);
      const float res = lg - m - __logf(se);
      if (lane < 16) out[(size_t)n * NC + j] = res;
    }
  }
}

extern "C" void kernel_launch(void* const* d_in, const int* in_sizes, int n_in,
                              void* d_out, int out_size, void* d_ws, size_t ws_size,
                              hipStream_t stream) {
  const float* x     = (const float*)d_in[0];
  const int*   ei    = (const int*)d_in[1];
  const float* W1    = (const float*)d_in[2];
  const float* b1    = (const float*)d_in[3];
  const float* W2    = (const float*)d_in[4];
  const float* b2    = (const float*)d_in[5];
  const float* beta2 = (const float*)d_in[6];
  float* out = (float*)d_out;

  char* ws = (char*)d_ws;
  size_t o = 0;
  auto alloc = [&](size_t bytes) -> void* {
    o = (o + 255) & ~(size_t)255;
    void* p = ws + o;
    o += bytes;
    return p;
  };
  u16*   h1     = (u16*)alloc((size_t)NN * NH * 2);
  u16*   h2     = (u16*)alloc((size_t)NN * NH * 2);
  float* rn1    = (float*)alloc((size_t)NN * 4);
  float* rn2    = (float*)alloc((size_t)NN * 4);
  int*   counts = (int*)alloc((size_t)NN * 4);
  int*   offs   = (int*)alloc((size_t)NN * 4);
  int*   cursor = (int*)alloc((size_t)NN * 4);
  int*   bsum   = (int*)alloc(1024 * 4);
  int*   csr    = (int*)alloc((size_t)NE * 4);

  const int* esrc = ei;
  const int* edst = ei + NE;

  const int nb = (NN + 255) / 256;   // 391
  const int nfeat = (NN + 63) / 64;  // 1563

  k_feat<<<nfeat, 256, 0, stream>>>(x, W1, b1, h1, rn1, counts);
  k_count<<<4096, 256, 0, stream>>>(edst, counts);
  k_scan1<<<nb, 256, 0, stream>>>(counts, bsum);
  k_scan2<<<1, 512, 0, stream>>>(bsum, nb);
  k_scan3<<<nb, 256, 0, stream>>>(counts, bsum, offs, cursor);
  k_fill<<<FILL_BLOCKS, 256, 0, stream>>>(esrc, edst, cursor, csr);
  k_prop<false><<<25000, 256, 0, stream>>>(h1, rn1, csr, offs, counts, nullptr,
                                           h2, rn2, nullptr, nullptr, nullptr);
  k_prop<true><<<25000, 256, 0, stream>>>(h2, rn2, csr, offs, counts, beta2,
                                          nullptr, nullptr, W2, b2, out);
}

// Round 4
// 551.577 us; speedup vs baseline: 1.3618x; 1.0335x over previous
//
#include <hip/hip_runtime.h>
#include <hip/hip_bf16.h>

#define NN 100000
#define NE 3200000
#define NF 512
#define NH 16
#define NC 16
#define EPSF 1e-12f

// XCD-exclusive dst partitioning for CSR build: group g (= blockIdx & 7, which
// round-robins onto XCD g) exclusively owns dst range [g*RANGE,(g+1)*RANGE).
// Its csr window (1.6 MB) + cursor window (50 KB) live in ONE XCD's L2 ->
// full-line clean writebacks, no cross-XCD partial-line eviction, local atomics.
#define NXCD 8
#define RANGE ((NN + NXCD - 1) / NXCD)     // 12500
#define FILL_BLOCKS 2048                   // 256 blocks/group -> 8 blocks/CU on one XCD

typedef unsigned short u16;

__device__ __forceinline__ float bf2f(u16 v) {
  return __uint_as_float(((unsigned int)v) << 16);
}
__device__ __forceinline__ u16 f2bf(float f) {
  unsigned int u = __float_as_uint(f);
  u += 0x7fffu + ((u >> 16) & 1u);   // round-to-nearest-even
  return (u16)(u >> 16);
}

// ---------------- Kernel A: h1 = relu(x@W1 + b1), rnorm1; also zero counts ----
// Block = 4 waves = 64 rows. Wave q owns K-quarter [q*128,(q+1)*128) for all 64
// rows (lane = row). W1 address is wave-uniform -> s_load through K$ (SGPRs,
// zero VGPR cost); FMA = v_fmac(vgpr_x, sgpr_w). Cross-wave K-combine via LDS.
__global__ __launch_bounds__(256) void k_feat(const float* __restrict__ x,
    const float* __restrict__ W1, const float* __restrict__ b1,
    u16* __restrict__ h, float* __restrict__ rn, int* __restrict__ counts) {
  const int tid = threadIdx.x;
  // fold: zero the CSR count array (stream-ordered before k_count)
  for (int g = blockIdx.x * 256 + tid; g < NN; g += gridDim.x * 256)
    counts[g] = 0;

  __shared__ float part[4][64][20];   // [quarter][row][j], stride 20 (float4-aligned pad)

  const int lane = tid & 63;
  const int q = __builtin_amdgcn_readfirstlane(tid >> 6);  // wave-uniform K-quarter
  const int base = blockIdx.x * 64;
  int row = base + lane;
  if (row >= NN) row = NN - 1;        // clamp: dead rows compute garbage, writes guarded

  const float* wq = W1 + q * 128 * NH;                     // uniform
  const float4* xp = (const float4*)(x + (size_t)row * NF + q * 128);

  float acc[16];
  #pragma unroll
  for (int j = 0; j < 16; ++j) acc[j] = 0.f;

  #pragma unroll 2
  for (int kk = 0; kk < 32; ++kk) {   // 32 float4 steps of 4 k each
    const float4 xv = xp[kk];
    #pragma unroll
    for (int dk = 0; dk < 4; ++dk) {
      const float* wrow = wq + (kk * 4 + dk) * NH;         // uniform -> s_load
      const float xs = (dk == 0) ? xv.x : (dk == 1) ? xv.y : (dk == 2) ? xv.z : xv.w;
      #pragma unroll
      for (int j = 0; j < 16; ++j)
        acc[j] = fmaf(xs, wrow[j], acc[j]);
    }
  }

  #pragma unroll
  for (int j4 = 0; j4 < 4; ++j4)
    *(float4*)&part[q][lane][j4 * 4] =
        make_float4(acc[j4 * 4], acc[j4 * 4 + 1], acc[j4 * 4 + 2], acc[j4 * 4 + 3]);
  __syncthreads();

  // epilogue: thread (r2, jg) sums 4 quarters for 4 j's, relu, norm, store
  const int r2 = tid >> 2;            // 0..63
  const int jg = (tid & 3) * 4;       // j-group base
  const int orow = base + r2;
  float o[4];
  #pragma unroll
  for (int jj = 0; jj < 4; ++jj) {
    const int j = jg + jj;
    float s = part[0][r2][j] + part[1][r2][j] + part[2][r2][j] + part[3][r2][j];
    o[jj] = fmaxf(s + b1[j], 0.f);
  }
  float ss = o[0] * o[0] + o[1] * o[1] + o[2] * o[2] + o[3] * o[3];
  ss += __shfl_xor(ss, 1, 64);
  ss += __shfl_xor(ss, 2, 64);
  const float rv = 1.0f / fmaxf(sqrtf(ss), EPSF);
  if (orow < NN) {
    ushort4 hv;
    hv.x = f2bf(o[0]); hv.y = f2bf(o[1]); hv.z = f2bf(o[2]); hv.w = f2bf(o[3]);
    *(ushort4*)(h + (size_t)orow * NH + jg) = hv;
    if ((tid & 3) == 0) rn[orow] = rv;
  }
}

// ---------------- CSR build ----------------
// XCD-partitioned count: group g sweeps all dsts, counts only its range.
__global__ __launch_bounds__(256) void k_count(const int* __restrict__ dst,
                                               int* __restrict__ counts) {
  const int grp = blockIdx.x & (NXCD - 1);
  const int gb  = blockIdx.x >> 3;
  const int t0  = gb * 256 + (int)threadIdx.x;
  const int gstride = (FILL_BLOCKS / NXCD) * 256;   // 65536
  const int lo = grp * RANGE;
  const int hi = (lo + RANGE < NN) ? lo + RANGE : NN;
  for (int e = t0; e < NE; e += gstride) {
    const int d = dst[e];
    if (d >= lo && d < hi) atomicAdd(&counts[d], 1);
  }
}

__global__ void k_scan1(const int* __restrict__ counts, int* __restrict__ bsum) {
  __shared__ int sm[256];
  const int tid = threadIdx.x;
  const int i = blockIdx.x * 256 + tid;
  sm[tid] = (i < NN) ? counts[i] : 0;
  __syncthreads();
  for (int s = 128; s > 0; s >>= 1) {
    if (tid < s) sm[tid] += sm[tid + s];
    __syncthreads();
  }
  if (tid == 0) bsum[blockIdx.x] = sm[0];
}

__global__ void k_scan2(int* __restrict__ bsum, int nb) {
  __shared__ int sm[512];
  const int tid = threadIdx.x;
  const int v = (tid < nb) ? bsum[tid] : 0;
  sm[tid] = v;
  __syncthreads();
  for (int s = 1; s < 512; s <<= 1) {
    int t = (tid >= s) ? sm[tid - s] : 0;
    __syncthreads();
    sm[tid] += t;
    __syncthreads();
  }
  if (tid < nb) bsum[tid] = sm[tid] - v;   // exclusive
}

__global__ void k_scan3(const int* __restrict__ counts, const int* __restrict__ bsum,
                        int* __restrict__ offs, int* __restrict__ cursor) {
  __shared__ int sm[256];
  const int tid = threadIdx.x;
  const int i = blockIdx.x * 256 + tid;
  const int v = (i < NN) ? counts[i] : 0;
  sm[tid] = v;
  __syncthreads();
  for (int s = 1; s < 256; s <<= 1) {
    int t = (tid >= s) ? sm[tid - s] : 0;
    __syncthreads();
    sm[tid] += t;
    __syncthreads();
  }
  const int excl = sm[tid] - v + bsum[blockIdx.x];
  if (i < NN) { offs[i] = excl; cursor[i] = excl; }
}

// XCD-partitioned fill: group g (one XCD) exclusively scatters its dst range.
__global__ __launch_bounds__(256) void k_fill(const int* __restrict__ srcs,
                                              const int* __restrict__ dsts,
                                              int* __restrict__ cursor,
                                              int* __restrict__ csr) {
  const int grp = blockIdx.x & (NXCD - 1);
  const int gb  = blockIdx.x >> 3;
  const int t0  = gb * 256 + (int)threadIdx.x;
  const int gstride = (FILL_BLOCKS / NXCD) * 256;   // 65536
  const int lo = grp * RANGE;
  const int hi = (lo + RANGE < NN) ? lo + RANGE : NN;
  for (int e = t0; e < NE; e += gstride) {
    const int d = dsts[e];
    if (d >= lo && d < hi) {
      const int slot = atomicAdd(&cursor[d], 1);
      csr[slot] = srcs[e];
    }
  }
}

// ---------------- Prop: wave per node, 16 lanes per edge, 4 edges in flight ---
// Softmax shift skipped: logits in [-|beta|, |beta|]; out = (sum w*h_src)/(sum w).
// Self-loop = virtual edge i == deg with src = n.
template <bool FINAL>
__global__ __launch_bounds__(256) void k_prop(const u16* __restrict__ hp,
    const float* __restrict__ rnp, const int* __restrict__ csr,
    const int* __restrict__ offs, const int* __restrict__ cnts,
    const float* __restrict__ betap,
    u16* __restrict__ ho, float* __restrict__ rno,
    const float* __restrict__ W2, const float* __restrict__ b2,
    float* __restrict__ out) {
  const int tid  = threadIdx.x;
  const int lane = tid & 63;
  const int j    = lane & 15;
  const int es   = lane >> 4;
  const int wid  = blockIdx.x * (blockDim.x >> 6) + (tid >> 6);
  const int nw   = gridDim.x * (blockDim.x >> 6);
  const float beta = betap ? betap[0] : 1.0f;

  float w2r[16];
  float b2j = 0.f;
  if (FINAL) {
    #pragma unroll
    for (int k = 0; k < 16; ++k) w2r[k] = W2[k * NC + j];
    b2j = b2[j];
  }

  for (int n = wid; n < NN; n += nw) {
    const int off = offs[n];
    const int deg = cnts[n];
    const float hd  = bf2f(hp[(size_t)n * NH + j]);
    const float rnd = rnp[n];
    const float brd = beta * rnd;
    float acc = 0.f, ssum = 0.f;
    const int total = deg + 1;            // + self loop
    for (int i = es; i < total; i += 4) {
      const int src = (i < deg) ? csr[off + i] : n;
      const float hs  = bf2f(hp[(size_t)src * NH + j]);
      const float rns = rnp[src];
      float p = hs * hd;                  // 16-dim dot via 16-lane reduce
      p += __shfl_xor(p, 1, 64);
      p += __shfl_xor(p, 2, 64);
      p += __shfl_xor(p, 4, 64);
      p += __shfl_xor(p, 8, 64);
      const float w = __expf(brd * rns * p);
      acc = fmaf(w, hs, acc);
      ssum += w;
    }
    acc  += __shfl_xor(acc, 16, 64);      // combine the 4 edge slots
    acc  += __shfl_xor(acc, 32, 64);
    ssum += __shfl_xor(ssum, 16, 64);
    ssum += __shfl_xor(ssum, 32, 64);
    const float o = acc / ssum;

    if (!FINAL) {
      float ss = o * o;
      ss += __shfl_xor(ss, 1, 64);
      ss += __shfl_xor(ss, 2, 64);
      ss += __shfl_xor(ss, 4, 64);
      ss += __shfl_xor(ss, 8, 64);
      float rv = 1.0f / fmaxf(sqrtf(ss), EPSF);
      if (lane < 16) ho[(size_t)n * NH + j] = f2bf(o);
      if (lane == 0) rno[n] = rv;
    } else {
      // logits = o(row) @ W2 + b2, then log_softmax across 16 lanes
      float lg = b2j;
      #pragma unroll
      for (int k = 0; k < 16; ++k) {
        const float hk = __shfl(o, k, 64);
        lg = fmaf(hk, w2r[k], lg);
      }
      float m = lg;
      m = fmaxf(m, __shfl_xor(m, 1, 64));
      m = fmaxf(m, __shfl_xor(m, 2, 64));
      m = fmaxf(m, __shfl_xor(m, 4, 64));
      m = fmaxf(m, __shfl_xor(m, 8, 64));
      float e = __expf(lg - m);
      float se = e;
      se += __shfl_xor(se, 1, 64);
      se += __shfl_xor(se, 2, 64);
      se += __shfl_xor(se, 4, 64);
      se += __shfl_xor(se, 8, 64);
      const float res = lg - m - __logf(se);
      if (lane < 16) out[(size_t)n * NC + j] = res;
    }
  }
}

extern "C" void kernel_launch(void* const* d_in, const int* in_sizes, int n_in,
                              void* d_out, int out_size, void* d_ws, size_t ws_size,
                              hipStream_t stream) {
  const float* x     = (const float*)d_in[0];
  const int*   ei    = (const int*)d_in[1];
  const float* W1    = (const float*)d_in[2];
  const float* b1    = (const float*)d_in[3];
  const float* W2    = (const float*)d_in[4];
  const float* b2    = (const float*)d_in[5];
  const float* beta2 = (const float*)d_in[6];
  float* out = (float*)d_out;

  char* ws = (char*)d_ws;
  size_t o = 0;
  auto alloc = [&](size_t bytes) -> void* {
    o = (o + 255) & ~(size_t)255;
    void* p = ws + o;
    o += bytes;
    return p;
  };
  u16*   h1     = (u16*)alloc((size_t)NN * NH * 2);
  u16*   h2     = (u16*)alloc((size_t)NN * NH * 2);
  float* rn1    = (float*)alloc((size_t)NN * 4);
  float* rn2    = (float*)alloc((size_t)NN * 4);
  int*   counts = (int*)alloc((size_t)NN * 4);
  int*   offs   = (int*)alloc((size_t)NN * 4);
  int*   cursor = (int*)alloc((size_t)NN * 4);
  int*   bsum   = (int*)alloc(1024 * 4);
  int*   csr    = (int*)alloc((size_t)NE * 4);

  const int* esrc = ei;
  const int* edst = ei + NE;

  const int nb = (NN + 255) / 256;   // 391
  const int nfeat = (NN + 63) / 64;  // 1563

  k_feat<<<nfeat, 256, 0, stream>>>(x, W1, b1, h1, rn1, counts);
  k_count<<<FILL_BLOCKS, 256, 0, stream>>>(edst, counts);
  k_scan1<<<nb, 256, 0, stream>>>(counts, bsum);
  k_scan2<<<1, 512, 0, stream>>>(bsum, nb);
  k_scan3<<<nb, 256, 0, stream>>>(counts, bsum, offs, cursor);
  k_fill<<<FILL_BLOCKS, 256, 0, stream>>>(esrc, edst, cursor, csr);
  k_prop<false><<<25000, 256, 0, stream>>>(h1, rn1, csr, offs, counts, nullptr,
                                           h2, rn2, nullptr, nullptr, nullptr);
  k_prop<true><<<25000, 256, 0, stream>>>(h2, rn2, csr, offs, counts, beta2,
                                          nullptr, nullptr, W2, b2, out);
}